// Round 4
// baseline (391.596 us; speedup 1.0000x reference)
//
#include <hip/hip_runtime.h>
#include <stdint.h>

// Problem constants (reference: M,K,N = 8192,4096,4096)
#define GM 8192
#define GK 4096
#define GN 4096

typedef int v4i __attribute__((ext_vector_type(4)));

__device__ __forceinline__ void async_load16(const void* gptr, void* lptr) {
  __builtin_amdgcn_global_load_lds(
      (const __attribute__((address_space(1))) void*)gptr,
      (__attribute__((address_space(3))) void*)lptr,
      16 /*bytes*/, 0 /*offset*/, 0 /*aux*/);
}

// ---------------- Kernel 1: fused prep (unchanged) ----------------
#define TBLK ((GN / 64) * (GK / 64))      // 4096 transpose blocks
#define QBLK (GM * GK / 4 / 256)          // 32768 quant blocks

__global__ __launch_bounds__(256) void prep_kernel(
    const float* __restrict__ x, int8_t* __restrict__ qx,
    const float* __restrict__ scale_p, const float* __restrict__ off_p,
    const int* __restrict__ B, int8_t* __restrict__ Bt) {
  __shared__ int tile32[64][65];
  const int b = blockIdx.x;
  const int t = threadIdx.x;
  if (b < TBLK) {
    const int n0 = (b & 63) * 64;
    const int k0 = (b >> 6) * 64;
#pragma unroll
    for (int r = 0; r < 4; ++r) {
      const int kl = r * 16 + (t >> 4);
      const int nl = (t & 15) * 4;
      const int4 v = *(const int4*)(B + (size_t)(k0 + kl) * GN + n0 + nl);
      *(int4*)&tile32[kl][nl] = v;
    }
    __syncthreads();
    const int nl = t >> 2;
    const int kc = (t & 3) * 16;
    v4i out;
#pragma unroll
    for (int w = 0; w < 4; ++w) {
      int p = 0;
#pragma unroll
      for (int j = 0; j < 4; ++j)
        p |= (tile32[kc + w * 4 + j][nl] & 0xff) << (8 * j);
      out[w] = p;
    }
    *(v4i*)(Bt + (size_t)(n0 + nl) * GK + k0 + kc) = out;
  } else {
    const int i = (b - TBLK) * 256 + t;
    const float s = scale_p[0], o = off_p[0];
    const float4 f = ((const float4*)x)[i];
    float a0 = fminf(fmaxf(rintf(f.x * s + o), -128.f), 127.f);
    float b0 = fminf(fmaxf(rintf(f.y * s + o), -128.f), 127.f);
    float c0 = fminf(fmaxf(rintf(f.z * s + o), -128.f), 127.f);
    float d0 = fminf(fmaxf(rintf(f.w * s + o), -128.f), 127.f);
    int packed = (((int)a0) & 0xff) | ((((int)b0) & 0xff) << 8) |
                 ((((int)c0) & 0xff) << 16) | ((((int)d0) & 0xff) << 24);
    ((int*)qx)[i] = packed;
  }
}

// ---------------- Kernel 2: int8 GEMM, 256x256, BK=128, 8 waves ------
// Round-4 == round-3 resubmit (round-3 bench was an infra failure, zero
// signal). Faithful m201 8-phase port (i8 BK=128 is byte-identical to
// bf16 BK=64). 4 phases per K-tile, each:
//   { ds_read subtile (8 or 4 b128); stage 2 DMA quarters; BAR;
//     lgkmcnt(0); setprio(1); 16 MFMA; setprio(0); [counted vmcnt]; BAR }
// Phase = (m-half, kstep): P0=(lo,k0) P1=(lo,k1) P2=(hi,k0) P3=(hi,k1).
// B-frags bK0/bK1 read once (P0/P1), reused at P2/P3.
// Stage stream for tile kt+1 (into buf^1), sorted by consumption need:
//   P0: A-q0,A-q2   (needed at kt+1 P0 by ahalf 0/1 waves)
//   P1: B-q0,B-q1   (all B quarters needed at kt+1 P0)
//   P2: B-q2,B-q3
//   P3: A-q1,A-q3   (needed only at kt+1 P2)
// Counted waits (never 0 in loop), per-wave queue oldest->newest at
//   P3-end: [Aq0,Aq2 | Bq0,Bq1 | Bq2,Bq3 | Aq1,Aq3] -> vmcnt(2) drains
//   the 6 quarters needed at next P0, keeps Aq1,Aq3 in flight.
//   P1-end: [Aq1,Aq3 | Aq0',Aq2' | Bq0',Bq1'] -> vmcnt(4) drains
//   Aq1,Aq3 needed at P2. Each wait is followed by BAR, so the union of
//   all waves' own-load drains publishes the full region (m201 logic).
// Race-freedom of stages: each quarter overwritten >=2 barriers after
// its last reader's lgkmcnt(0)+BAR (A-q0/q2 last read at prev-tile P1;
// B at prev-tile P1; A-q1/q3 at prev-tile P3).
#define NT (GK / 128)  // 32 K-tiles

__global__ __launch_bounds__(512, 2) void gemm_i8_kernel(
    const int8_t* __restrict__ A, const int8_t* __restrict__ Bt,
    const int* __restrict__ bias, const float* __restrict__ deq,
    float* __restrict__ C) {
  __shared__ __align__(16) int8_t Al[2][2][128 * 128];  // 64 KB
  __shared__ __align__(16) int8_t Bl[2][2][128 * 128];  // 64 KB

  const int t = threadIdx.x;
  const int lane = t & 63;
  const int wid = t >> 6;

  // T1: XCD-aware swizzle, grid = 512 (bijective, 512%8==0)
  const int bid = blockIdx.x;
  const int swz = (bid & 7) * 64 + (bid >> 3);
  const int m0 = (swz >> 4) * 256;  // 32 M-blocks
  const int n0 = (swz & 15) * 256;  // 16 N-blocks

  const int ahalf = wid >> 2;       // wave's A half (M): rows ahalf*128..+127
  const int wm = ahalf * 128;
  const int wn = (wid & 3) * 64;    // wave's 64-col N slice (B rows wn..wn+63)

  // T2 swizzle constants (verified absmax 0.0 in R1/R2): LDS granule g of
  // row r stored at g ^ (r&7); fragment rows have row&7 == fr&7.
  const int fr = lane & 15;
  const int kq = lane >> 4;
  const int sw0 = ((kq) ^ (fr & 7)) * 16;      // kstep 0 (k-bytes 0..63)
  const int sw1 = ((4 + kq) ^ (fr & 7)) * 16;  // kstep 1 (k-bytes 64..127)

  // Staging: thread t covers row srow (t>>3) of a 64-row quarter, granule
  // t&7; source col pre-swizzled, LDS dest linear (q*8192 + t*16).
  const int srow = t >> 3;                         // 0..63
  const int lg16 = (((t & 7) ^ (srow & 7)) * 16);  // swizzled source col
  const int ldst = t * 16;                         // linear LDS dest

  v4i acc[8][4];
  const v4i vz = {0, 0, 0, 0};
#pragma unroll
  for (int m = 0; m < 8; ++m)
#pragma unroll
    for (int n = 0; n < 4; ++n) acc[m][n] = vz;

// Stage one 64-row quarter (8 KB) of A or B of tile T_: 1 DMA per thread.
#define STAGE_AQ(T_, q_)                                               \
  do {                                                                 \
    const int8_t* s_ = A + (size_t)(m0 + (q_) * 64 + srow) * GK +      \
                       (size_t)(T_) * 128 + lg16;                      \
    async_load16(s_, &Al[(T_) & 1][0][0] + (q_) * 8192 + ldst);        \
  } while (0)
#define STAGE_BQ(T_, q_)                                               \
  do {                                                                 \
    const int8_t* s_ = Bt + (size_t)(n0 + (q_) * 64 + srow) * GK +     \
                       (size_t)(T_) * 128 + lg16;                      \
    async_load16(s_, &Bl[(T_) & 1][0][0] + (q_) * 8192 + ldst);        \
  } while (0)

// Read 4 A m-frags (m-half mh_, one kstep) / 4 B n-frags (one kstep).
#define READ_A4(dst, mh_, swz_)                                        \
  do {                                                                 \
    const int8_t* p_ = &Al[buf][0][0] +                                \
        (size_t)(wm + (mh_) * 64 + fr) * 128 + (swz_);                 \
    _Pragma("unroll") for (int i_ = 0; i_ < 4; ++i_)                   \
        dst[i_] = *(const v4i*)(p_ + i_ * 2048);                       \
  } while (0)
#define READ_B4(dst, swz_)                                             \
  do {                                                                 \
    const int8_t* p_ = &Bl[buf][0][0] + (size_t)(wn + fr) * 128 + (swz_); \
    _Pragma("unroll") for (int i_ = 0; i_ < 4; ++i_)                   \
        dst[i_] = *(const v4i*)(p_ + i_ * 2048);                       \
  } while (0)

// 16 MFMA: m-frags MB..MB+3 x n-frags 0..3.
#define QUAD16(AF, BF, MB)                                             \
  do {                                                                 \
    _Pragma("unroll") for (int mi_ = 0; mi_ < 4; ++mi_) {              \
      _Pragma("unroll") for (int ni_ = 0; ni_ < 4; ++ni_) {            \
        acc[(MB) + mi_][ni_] = __builtin_amdgcn_mfma_i32_16x16x64_i8(  \
            AF[mi_], BF[ni_], acc[(MB) + mi_][ni_], 0, 0, 0);          \
      }                                                                \
    }                                                                  \
  } while (0)

#define LGKM0 asm volatile("s_waitcnt lgkmcnt(0)" ::: "memory")
#define VMC4 asm volatile("s_waitcnt vmcnt(4)" ::: "memory")
#define VMC2 asm volatile("s_waitcnt vmcnt(2)" ::: "memory")
#define VMC0 asm volatile("s_waitcnt vmcnt(0)" ::: "memory")
#define BAR __builtin_amdgcn_s_barrier()
#define PRIO1 __builtin_amdgcn_s_setprio(1)
#define PRIO0 __builtin_amdgcn_s_setprio(0)

  v4i aL0[4], aL1[4], aH0[4], aH1[4], bK0[4], bK1[4];

  // Prologue: tile 0 fully resident + published.
  STAGE_AQ(0, 0); STAGE_AQ(0, 2);
  STAGE_BQ(0, 0); STAGE_BQ(0, 1); STAGE_BQ(0, 2); STAGE_BQ(0, 3);
  STAGE_AQ(0, 1); STAGE_AQ(0, 3);
  VMC0;
  BAR;

#pragma unroll 2
  for (int kt = 0; kt < NT - 1; ++kt) {  // stages of kt+1 always valid
    const int buf = kt & 1;
    // ---- P0: (m-lo, k0)
    READ_A4(aL0, 0, sw0);
    READ_B4(bK0, sw0);
    STAGE_AQ(kt + 1, 0); STAGE_AQ(kt + 1, 2);
    BAR;
    LGKM0;
    PRIO1; QUAD16(aL0, bK0, 0); PRIO0;
    BAR;
    // ---- P1: (m-lo, k1)
    READ_A4(aL1, 0, sw1);
    READ_B4(bK1, sw1);
    STAGE_BQ(kt + 1, 0); STAGE_BQ(kt + 1, 1);
    BAR;
    LGKM0;
    PRIO1; QUAD16(aL1, bK1, 0); PRIO0;
    VMC4;  // drain A-q1,q3 of THIS tile (staged prev P3) for P2's reads
    BAR;
    // ---- P2: (m-hi, k0), reuse bK0
    READ_A4(aH0, 1, sw0);
    STAGE_BQ(kt + 1, 2); STAGE_BQ(kt + 1, 3);
    BAR;
    LGKM0;
    PRIO1; QUAD16(aH0, bK0, 4); PRIO0;
    BAR;
    // ---- P3: (m-hi, k1), reuse bK1
    READ_A4(aH1, 1, sw1);
    STAGE_AQ(kt + 1, 1); STAGE_AQ(kt + 1, 3);
    BAR;
    LGKM0;
    PRIO1; QUAD16(aH1, bK1, 4); PRIO0;
    VMC2;  // drain 6 oldest: A-q0,q2 + B-all of tile kt+1 for next P0
    BAR;
  }
  // ---- Peeled kt = NT-1 (buf 1): no stages; only A-q1,q3 still in flight.
  {
    const int buf = (NT - 1) & 1;
    READ_A4(aL0, 0, sw0);
    READ_B4(bK0, sw0);
    READ_A4(aL1, 0, sw1);
    READ_B4(bK1, sw1);
    QUAD16(aL0, bK0, 0);
    QUAD16(aL1, bK1, 0);
    VMC0;  // own A-q1,q3 loads drained...
    BAR;   // ...and every wave's (union covers the region)
    READ_A4(aH0, 1, sw0);
    READ_A4(aH1, 1, sw1);
    QUAD16(aH0, bK0, 4);
    QUAD16(aH1, bK1, 4);
  }

  // Epilogue. C/D layout: col = lane&15, row = (lane>>4)*4 + reg (m89).
  const int col = lane & 15;
  const int rq = (lane >> 4) * 4;
#pragma unroll
  for (int n = 0; n < 4; ++n) {
    const int gc = n0 + wn + n * 16 + col;
    const float d = deq[gc];
    const int bs = bias[gc];
#pragma unroll
    for (int m = 0; m < 8; ++m) {
      const int gr = m0 + wm + m * 16 + rq;
#pragma unroll
      for (int r = 0; r < 4; ++r)
        C[(size_t)(gr + r) * GN + gc] = (float)(acc[m][n][r] + bs) * d;
    }
  }
#undef STAGE_AQ
#undef STAGE_BQ
#undef READ_A4
#undef READ_B4
#undef QUAD16
#undef LGKM0
#undef VMC4
#undef VMC2
#undef VMC0
#undef BAR
#undef PRIO1
#undef PRIO0
}

extern "C" void kernel_launch(void* const* d_in, const int* in_sizes, int n_in,
                              void* d_out, int out_size, void* d_ws, size_t ws_size,
                              hipStream_t stream) {
  const float* x = (const float*)d_in[0];
  const int* qw = (const int*)d_in[1];        // int8 in reference -> int32 on device
  const float* act_scale = (const float*)d_in[2];
  const float* act_offset = (const float*)d_in[3];
  const float* deq = (const float*)d_in[4];
  const int* bias = (const int*)d_in[5];
  float* out = (float*)d_out;

  // Workspace: qx [M*K int8] then Bt [N*K int8]  (48 MB total)
  int8_t* qx = (int8_t*)d_ws;
  int8_t* Bt = (int8_t*)d_ws + (size_t)GM * GK;

  prep_kernel<<<TBLK + QBLK, 256, 0, stream>>>(x, qx, act_scale, act_offset, qw, Bt);
  gemm_i8_kernel<<<dim3((GM / 256) * (GN / 256)), 512, 0, stream>>>(qx, Bt, bias, deq, out);
}